// Round 4
// baseline (340.330 us; speedup 1.0000x reference)
//
#include <hip/hip_runtime.h>
#include <stdint.h>

#define IN_F 256
#define OUT_F 128
#define NCOLS 1024   // 768 node-msg cols + 128 sum-slice + 128 self
#define GBM 64       // gemm rows per block

using bf16x8 = __attribute__((ext_vector_type(8))) __bf16;
using f32x4  = __attribute__((ext_vector_type(4))) float;

static __device__ __forceinline__ unsigned short f2bf(float f) {
    unsigned u = __float_as_uint(f);
    u = u + 0x7fffu + ((u >> 16) & 1u);   // RNE
    return (unsigned short)(u >> 16);
}
static __device__ __forceinline__ float bf_lo(unsigned u) { return __uint_as_float(u << 16); }
static __device__ __forceinline__ float bf_hi(unsigned u) { return __uint_as_float(u & 0xffff0000u); }

static __device__ __forceinline__ void async_load16(const void* g, void* l) {
    __builtin_amdgcn_global_load_lds(
        (__attribute__((address_space(1))) void*)g,
        (__attribute__((address_space(3))) void*)l,
        16, 0, 0);
}

// ---- h (f32) -> bf16 ----
__global__ void k_conv_h(const float* __restrict__ h, unsigned short* __restrict__ hb, int total8) {
    int i = blockIdx.x * blockDim.x + threadIdx.x;
    if (i >= total8) return;
    const float4* src = ((const float4*)h) + (size_t)i * 2;
    float4 a = src[0], b = src[1];
    union { unsigned short us[8]; uint4 v; } u;
    u.us[0] = f2bf(a.x); u.us[1] = f2bf(a.y); u.us[2] = f2bf(a.z); u.us[3] = f2bf(a.w);
    u.us[4] = f2bf(b.x); u.us[5] = f2bf(b.y); u.us[6] = f2bf(b.z); u.us[7] = f2bf(b.w);
    ((uint4*)hb)[i] = u.v;
}

// ---- Wt[1024][256] = [W_node | sum(W_node slices) | W_self]^T, bf16 ----
__global__ void k_conv_w(const float* __restrict__ Wn, const float* __restrict__ Ws,
                         unsigned short* __restrict__ Wt, int total) {
    int i = blockIdx.x * blockDim.x + threadIdx.x;   // i = k*1024 + c
    if (i >= total) return;
    int k = i >> 10, c = i & 1023;
    float v;
    if (c < 768) {
        v = Wn[(size_t)k * 768 + c];
    } else if (c < 896) {
        int j = c - 768; v = 0.f;
#pragma unroll
        for (int s = 0; s < 6; ++s) v += Wn[(size_t)k * 768 + s * 128 + j];
    } else {
        v = Ws[(size_t)k * 128 + (c - 896)];
    }
    Wt[(size_t)c * IN_F + k] = f2bf(v);
}

// ---- combined bias vector bvec[1024] ----
__global__ void k_conv_b(const float* __restrict__ bn, const float* __restrict__ bs,
                         float* __restrict__ bvec) {
    int c = blockIdx.x * blockDim.x + threadIdx.x;
    if (c >= NCOLS) return;
    float v;
    if (c < 768) v = bn[c];
    else if (c < 896) {
        int j = c - 768; v = 0.f;
#pragma unroll
        for (int s = 0; s < 6; ++s) v += bn[s * 128 + j];
    } else v = bs[c - 896];
    bvec[c] = v;
}

// ---- GEMM v2: block = 64 rows x 1024 cols; A staged once; B direct from L2 ----
__global__ void __launch_bounds__(256, 3) k_gemm(
    const unsigned short* __restrict__ hb,
    const unsigned short* __restrict__ Wt,
    const float* __restrict__ bvec,
    const float* __restrict__ norm,
    unsigned short* __restrict__ P, int N)
{
    __shared__ char Alds[GBM * 512];                 // 32 KB, granule-swizzled
    __shared__ unsigned short Pst[GBM * 128];        // 16 KB store-staging, swizzled

    const int tid = threadIdx.x;
    const int wid = tid >> 6, lane = tid & 63;
    const int lrow = lane & 15, s = lane >> 4;
    const int wr = wid >> 1, wc = wid & 1;
    const int r0 = blockIdx.x * GBM;

    // ---- stage A once: LDS[row][gl] = hb[row][(gl ^ (row&7))*8 ..] ----
#pragma unroll
    for (int it = 0; it < 8; ++it) {
        int d = it * 256 + tid;          // granule index 0..2047
        int row = d >> 5, gl = d & 31;
        int gsrc = gl ^ (row & 7);
        int grow = r0 + row; if (grow >= N) grow = N - 1;
        async_load16(hb + (size_t)grow * IN_F + gsrc * 8, Alds + d * 16);
    }

    // norm for this lane's 8 output rows (loaded while A stages)
    float nrmv[2][4];
#pragma unroll
    for (int m = 0; m < 2; ++m)
#pragma unroll
        for (int r = 0; r < 4; ++r) {
            int rg = r0 + wr * 32 + m * 16 + s * 4 + r;
            nrmv[m][r] = norm[rg < N ? rg : N - 1];
        }

    // A fragment byte offsets: logical granule (kk*4+s) of row, stored swizzled
    int a_off[2][8];
#pragma unroll
    for (int m = 0; m < 2; ++m) {
        const int row = wr * 32 + m * 16 + lrow;
        const int x = row & 7;
#pragma unroll
        for (int kk = 0; kk < 8; ++kk)
            a_off[m][kk] = row * 512 + ((kk * 4 + s) ^ x) * 16;
    }

    const unsigned short* Bp = Wt + (size_t)(wc * 64 + lrow) * IN_F + s * 8;

    __syncthreads();   // A staged (compiler drains vmcnt at barrier)

    for (int ct = 0; ct < 8; ++ct) {
        const unsigned short* Bct = Bp + (size_t)ct * 128 * IN_F;
        f32x4 acc[2][4] = {};

#pragma unroll
        for (int kk = 0; kk < 8; ++kk) {
            bf16x8 a0 = *(const bf16x8*)(Alds + a_off[0][kk]);
            bf16x8 a1 = *(const bf16x8*)(Alds + a_off[1][kk]);
#pragma unroll
            for (int n = 0; n < 4; ++n) {
                bf16x8 b = *(const bf16x8*)(Bct + n * 16 * IN_F + kk * 32);
                acc[0][n] = __builtin_amdgcn_mfma_f32_16x16x32_bf16(a0, b, acc[0][n], 0, 0, 0);
                acc[1][n] = __builtin_amdgcn_mfma_f32_16x16x32_bf16(a1, b, acc[1][n], 0, 0, 0);
            }
        }

        // ---- epilogue: bias + norm, bf16, stage in LDS, coalesced store ----
        __syncthreads();   // previous col-tile's Pst reads done
        const bool doNorm = (ct < 7);
#pragma unroll
        for (int m = 0; m < 2; ++m) {
            const int rowl = wr * 32 + m * 16 + s * 4;
#pragma unroll
            for (int n = 0; n < 4; ++n) {
                const int col = wc * 64 + n * 16 + lrow;
                const float bv = bvec[ct * 128 + col];
                const int chunk = col >> 3, cb = col & 7;
#pragma unroll
                for (int r = 0; r < 4; ++r) {
                    float v = acc[m][n][r] + bv;
                    if (doNorm) v *= nrmv[m][r];
                    const int row = rowl + r;
                    Pst[row * 128 + ((chunk ^ (row & 7)) * 8 + cb)] = f2bf(v);
                }
            }
        }
        __syncthreads();

        const int ch = tid & 15;
#pragma unroll
        for (int rr = 0; rr < 4; ++rr) {
            const int rl = rr * 16 + (tid >> 4);
            const int rg = r0 + rl;
            if (rg < N) {
                uint4 v = *(const uint4*)&Pst[rl * 128 + ((ch ^ (rl & 7)) * 8)];
                *(uint4*)(P + (size_t)rg * NCOLS + ct * 128 + ch * 8) = v;
            }
        }
    }
}

// ---- histogram over dst ----
__global__ void k_hist(const int* __restrict__ dst, int* __restrict__ counts, int E) {
    int e = blockIdx.x * blockDim.x + threadIdx.x;
    if (e < E) atomicAdd(&counts[dst[e]], 1);
}

// ---- 3-phase exclusive scan over counts[N] ----
__global__ void __launch_bounds__(256) k_scan_a(const int* __restrict__ counts,
                                                int* __restrict__ offs,
                                                int* __restrict__ bsum, int N) {
    __shared__ int sm[256];
    int tid = threadIdx.x;
    int i = blockIdx.x * 256 + tid;
    int v = (i < N) ? counts[i] : 0;
    sm[tid] = v;
    __syncthreads();
#pragma unroll
    for (int st = 1; st < 256; st <<= 1) {
        int t = (tid >= st) ? sm[tid - st] : 0;
        __syncthreads();
        sm[tid] += t;
        __syncthreads();
    }
    if (i < N) offs[i] = sm[tid] - v;
    if (tid == 255) bsum[blockIdx.x] = sm[255];
}

__global__ void __launch_bounds__(256) k_scan_b(int* __restrict__ bsum, int NB) {
    __shared__ int sm[256];
    int tid = threadIdx.x;
    int v = (tid < NB) ? bsum[tid] : 0;
    sm[tid] = v;
    __syncthreads();
#pragma unroll
    for (int st = 1; st < 256; st <<= 1) {
        int t = (tid >= st) ? sm[tid - st] : 0;
        __syncthreads();
        sm[tid] += t;
        __syncthreads();
    }
    if (tid < NB) bsum[tid] = sm[tid] - v;
}

__global__ void k_scan_c(int* __restrict__ offs, const int* __restrict__ bsum,
                         int* __restrict__ cursor, int N) {
    int i = blockIdx.x * 256 + threadIdx.x;
    if (i >= N) return;
    int o = offs[i] + bsum[blockIdx.x];
    offs[i] = o;
    cursor[i] = o;
}

// ---- scatter edges into CSR order: pedge[slot] = {src, packed degs} ----
__global__ void k_scatter(const int* __restrict__ src, const int* __restrict__ dst,
                          const float* __restrict__ degrees,
                          int* __restrict__ cursor, uint2* __restrict__ pedge, int E) {
    int e = blockIdx.x * blockDim.x + threadIdx.x;
    if (e >= E) return;
    int d = dst[e];
    int slot = atomicAdd(&cursor[d], 1);
    unsigned pk = 0;
#pragma unroll
    for (int i = 0; i < 6; ++i) {
        float df = degrees[(size_t)e * 6 + i];
        pk |= ((unsigned)df) << (4 * i);
    }
    pedge[slot] = make_uint2((unsigned)src[e], pk);
}

// ---- aggregate: lane-parallel metadata + LDS gather worklist ----
__global__ void __launch_bounds__(256) k_aggregate(
    const unsigned short* __restrict__ P,
    const int* __restrict__ row_start, const int* __restrict__ counts,
    const uint2* __restrict__ pedge,
    const float* __restrict__ norm, const float* __restrict__ W_edge,
    const float* __restrict__ bias, float* __restrict__ out, int N)
{
    __shared__ unsigned EL[4][192];
    const int wid = threadIdx.x >> 6;
    const int n = blockIdx.x * 4 + wid;
    if (n >= N) return;
    const int lane = threadIdx.x & 63;
    unsigned* el = EL[wid];

    float2 w[6];
#pragma unroll
    for (int i = 0; i < 6; ++i) w[i] = *(const float2*)(W_edge + i * OUT_F + lane * 2);

    const int beg = row_start[n];
    const int end = beg + counts[n];
    const unsigned* __restrict__ Pd = (const unsigned*)P;

    float Swd[6] = {0.f, 0.f, 0.f, 0.f, 0.f, 0.f};
    float g0 = 0.f, g1 = 0.f;

    for (int p0 = beg; p0 < end; p0 += 64) {
        const int t = p0 + lane;
        const bool valid = t < end;
        uint2 pe = valid ? pedge[t] : make_uint2(0u, 0u);
        const unsigned dp = pe.y;
        const float nr = (dp != 0u) ? norm[pe.x] : 0.f;

        unsigned zm = 0;
#pragma unroll
        for (int i = 0; i < 6; ++i) {
            int d = (dp >> (4 * i)) & 15;
            if (d == 0) zm |= (1u << i);
            Swd[i] += nr * (float)d;
        }
        const int z = __popc(zm);
        const int ne = (dp == 0u) ? 0 : ((z <= 2) ? (1 + z) : (6 - z));

        int x = ne;
#pragma unroll
        for (int st = 1; st < 64; st <<= 1) {
            int v = __shfl_up(x, st);
            if (lane >= st) x += v;
        }
        const int excl = x - ne;
        const int total = __shfl(x, 63);

        if (ne) {
            const unsigned base = pe.x * 512u;
            int wp = excl;
            if (z <= 2) {
                el[wp++] = base + 384u;
#pragma unroll
                for (int i = 0; i < 6; ++i)
                    if ((zm >> i) & 1u) el[wp++] = (base + i * 64u) | 0x80000000u;
            } else {
#pragma unroll
                for (int i = 0; i < 6; ++i)
                    if (!((zm >> i) & 1u)) el[wp++] = base + i * 64u;
            }
        }
        asm volatile("s_waitcnt lgkmcnt(0)" ::: "memory");

        int j = 0;
        for (; j + 4 <= total; j += 4) {
            unsigned e0 = el[j], e1 = el[j + 1], e2 = el[j + 2], e3 = el[j + 3];
            unsigned u0 = Pd[(e0 & 0x7fffffffu) + lane];
            unsigned u1 = Pd[(e1 & 0x7fffffffu) + lane];
            unsigned u2 = Pd[(e2 & 0x7fffffffu) + lane];
            unsigned u3 = Pd[(e3 & 0x7fffffffu) + lane];
            float s0 = __uint_as_float(0x3f800000u | (e0 & 0x80000000u));
            float s1 = __uint_as_float(0x3f800000u | (e1 & 0x80000000u));
            float s2 = __uint_as_float(0x3f800000u | (e2 & 0x80000000u));
            float s3 = __uint_as_float(0x3f800000u | (e3 & 0x80000000u));
            g0 += s0 * bf_lo(u0); g1 += s0 * bf_hi(u0);
            g0 += s1 * bf_lo(u1); g1 += s1 * bf_hi(u1);
            g0 += s2 * bf_lo(u2); g1 += s2 * bf_hi(u2);
            g0 += s3 * bf_lo(u3); g1 += s3 * bf_hi(u3);
        }
        for (; j < total; ++j) {
            unsigned e0 = el[j];
            unsigned u0 = Pd[(e0 & 0x7fffffffu) + lane];
            float s0 = __uint_as_float(0x3f800000u | (e0 & 0x80000000u));
            g0 += s0 * bf_lo(u0); g1 += s0 * bf_hi(u0);
        }
    }

    float b0 = 0.f, b1 = 0.f;
#pragma unroll
    for (int i = 0; i < 6; ++i) {
        float v = Swd[i];
#pragma unroll
        for (int st = 1; st < 64; st <<= 1) v += __shfl_xor(v, st);
        b0 += v * w[i].x;
        b1 += v * w[i].y;
    }

    const unsigned us = Pd[(size_t)n * 512 + 448 + lane];
    const float nd = norm[n];
    const float2 bv = *(const float2*)(bias + lane * 2);
    float2 o;
    o.x = fmaxf((g0 + b0) * nd + bf_lo(us) + bv.x, 0.f);
    o.y = fmaxf((g1 + b1) * nd + bf_hi(us) + bv.y, 0.f);
    *(float2*)(out + (size_t)n * OUT_F + lane * 2) = o;
}

extern "C" void kernel_launch(void* const* d_in, const int* in_sizes, int n_in,
                              void* d_out, int out_size, void* d_ws, size_t ws_size,
                              hipStream_t stream)
{
    const float* h       = (const float*)d_in[0];
    const float* degrees = (const float*)d_in[1];
    const float* norm    = (const float*)d_in[2];
    const int*   src     = (const int*)d_in[3];
    const int*   dst     = (const int*)d_in[4];
    const float* W_self  = (const float*)d_in[5];
    const float* b_self  = (const float*)d_in[6];
    const float* W_node  = (const float*)d_in[7];
    const float* b_node  = (const float*)d_in[8];
    const float* W_edge  = (const float*)d_in[9];
    const float* bias    = (const float*)d_in[10];
    float* out = (float*)d_out;

    const int N = in_sizes[2];   // norm [N,1]
    const int E = in_sizes[3];   // src [E]
    const int NB = (N + 255) / 256;

    char* ws = (char*)d_ws;
    size_t off = 0;
    auto alloc = [&](size_t sz) { size_t o = off; off = (off + sz + 255) & ~(size_t)255; return o; };
    unsigned short* P      = (unsigned short*)(ws + alloc((size_t)N * NCOLS * 2)); // 102.4 MB
    unsigned short* hb     = (unsigned short*)(ws + alloc((size_t)N * IN_F * 2));  // 25.6 MB
    unsigned short* Wt     = (unsigned short*)(ws + alloc((size_t)NCOLS * IN_F * 2));
    float*          bvec   = (float*)(ws + alloc(NCOLS * 4));
    int*            counts = (int*)(ws + alloc((size_t)N * 4));
    int*            offs   = (int*)(ws + alloc((size_t)N * 4));
    int*            cursor = (int*)(ws + alloc((size_t)N * 4));
    int*            bsum   = (int*)(ws + alloc((size_t)NB * 4));
    uint2*          pedge  = (uint2*)(ws + alloc((size_t)E * 8));                  // 6.4 MB

    hipMemsetAsync(counts, 0, (size_t)N * 4, stream);

    int t8 = N * (IN_F / 8);
    k_conv_h<<<(t8 + 255) / 256, 256, 0, stream>>>(h, hb, t8);

    int tw = IN_F * NCOLS;
    k_conv_w<<<(tw + 255) / 256, 256, 0, stream>>>(W_node, W_self, Wt, tw);
    k_conv_b<<<(NCOLS + 255) / 256, 256, 0, stream>>>(b_node, b_self, bvec);

    k_gemm<<<(N + GBM - 1) / GBM, 256, 0, stream>>>(hb, Wt, bvec, norm, P, N);

    k_hist<<<(E + 255) / 256, 256, 0, stream>>>(dst, counts, E);
    k_scan_a<<<NB, 256, 0, stream>>>(counts, offs, bsum, N);
    k_scan_b<<<1, 256, 0, stream>>>(bsum, NB);
    k_scan_c<<<NB, 256, 0, stream>>>(offs, bsum, cursor, N);
    k_scatter<<<(E + 255) / 256, 256, 0, stream>>>(src, dst, degrees, cursor, pedge, E);

    k_aggregate<<<(N + 3) / 4, 256, 0, stream>>>(P, offs, counts, pedge, norm, W_edge, bias, out, N);
}

// Round 5
// 233.291 us; speedup vs baseline: 1.4588x; 1.4588x over previous
//
#include <hip/hip_runtime.h>
#include <stdint.h>

#define IN_F 256
#define OUT_F 128
#define NCOLS 1024   // 768 node-msg cols + 128 sum-slice + 128 self
#define BM 64
#define BN 128
#define BK 32

using bf16x8 = __attribute__((ext_vector_type(8))) __bf16;
using f32x4  = __attribute__((ext_vector_type(4))) float;

static __device__ __forceinline__ unsigned short f2bf(float f) {
    unsigned u = __float_as_uint(f);
    u = u + 0x7fffu + ((u >> 16) & 1u);   // RNE
    return (unsigned short)(u >> 16);
}
static __device__ __forceinline__ float bf_lo(unsigned u) { return __uint_as_float(u << 16); }
static __device__ __forceinline__ float bf_hi(unsigned u) { return __uint_as_float(u & 0xffff0000u); }

static __device__ __forceinline__ void async_load16(const void* g, void* l) {
    __builtin_amdgcn_global_load_lds(
        (__attribute__((address_space(1))) void*)g,
        (__attribute__((address_space(3))) void*)l,
        16, 0, 0);
}

// ---- h (f32) -> bf16 ----
__global__ void k_conv_h(const float* __restrict__ h, unsigned short* __restrict__ hb, int total8) {
    int i = blockIdx.x * blockDim.x + threadIdx.x;
    if (i >= total8) return;
    const float4* src = ((const float4*)h) + (size_t)i * 2;
    float4 a = src[0], b = src[1];
    union { unsigned short us[8]; uint4 v; } u;
    u.us[0] = f2bf(a.x); u.us[1] = f2bf(a.y); u.us[2] = f2bf(a.z); u.us[3] = f2bf(a.w);
    u.us[4] = f2bf(b.x); u.us[5] = f2bf(b.y); u.us[6] = f2bf(b.z); u.us[7] = f2bf(b.w);
    ((uint4*)hb)[i] = u.v;
}

// ---- Wt[1024][256] = [W_node | sum(W_node slices) | W_self]^T, bf16 ----
__global__ void k_conv_w(const float* __restrict__ Wn, const float* __restrict__ Ws,
                         unsigned short* __restrict__ Wt, int total) {
    int i = blockIdx.x * blockDim.x + threadIdx.x;   // i = k*1024 + c
    if (i >= total) return;
    int k = i >> 10, c = i & 1023;
    float v;
    if (c < 768) {
        v = Wn[(size_t)k * 768 + c];
    } else if (c < 896) {
        int j = c - 768; v = 0.f;
#pragma unroll
        for (int s = 0; s < 6; ++s) v += Wn[(size_t)k * 768 + s * 128 + j];
    } else {
        v = Ws[(size_t)k * 128 + (c - 896)];
    }
    Wt[(size_t)c * IN_F + k] = f2bf(v);
}

// ---- combined bias vector bvec[1024] ----
__global__ void k_conv_b(const float* __restrict__ bn, const float* __restrict__ bs,
                         float* __restrict__ bvec) {
    int c = blockIdx.x * blockDim.x + threadIdx.x;
    if (c >= NCOLS) return;
    float v;
    if (c < 768) v = bn[c];
    else if (c < 896) {
        int j = c - 768; v = 0.f;
#pragma unroll
        for (int s = 0; s < 6; ++s) v += bn[s * 128 + j];
    } else v = bs[c - 896];
    bvec[c] = v;
}

// ---- GEMM v3: round-3 pipeline + XCD-chunked swizzle + staged coalesced C-store ----
__global__ void __launch_bounds__(256) k_gemm(
    const unsigned short* __restrict__ hb,
    const unsigned short* __restrict__ Wt,
    const float* __restrict__ bvec,
    const float* __restrict__ norm,
    unsigned short* __restrict__ P, int N, int rowsPerXcd)
{
    __shared__ char lds[(BM + BN) * BK * 2];       // 12 KB (A 4 KB, B 8 KB)
    __shared__ unsigned short Pst[BM * BN];        // 16 KB store staging
    char* Ab = lds;
    char* Bb = lds + BM * BK * 2;

    // --- XCD-chunked bijective swizzle: all 8 col-blocks of a row-strip on one XCD ---
    const int f  = blockIdx.x;
    const int xc = f & 7;                 // hardware XCD (round-robin assumption)
    const int j  = f >> 3;
    const int rs = xc * rowsPerXcd + (j >> 3);
    const int ct = j & 7;
    const int r0 = rs * BM;
    if (r0 >= N) return;
    const int c0 = ct * BN;

    const int tid = threadIdx.x;
    const int wid = tid >> 6, lane = tid & 63;
    const int lrow = lane & 15, s = lane >> 4;
    const int wr = wid >> 1, wc = wid & 1;

    const int arow = tid >> 2;
    const int achunk = (tid & 3) ^ ((arow >> 1) & 3);
    int agrow = r0 + arow; if (agrow >= N) agrow = N - 1;
    const unsigned short* aseg = hb + (size_t)agrow * IN_F + achunk * 8;

    const int bcol0 = tid >> 2;
    const int bchunk0 = (tid & 3) ^ ((bcol0 >> 1) & 3);
    const unsigned short* bseg0 = Wt + (size_t)(c0 + bcol0) * IN_F + bchunk0 * 8;
    const int idx1 = tid + 256;
    const int bcol1 = idx1 >> 2;
    const int bchunk1 = (idx1 & 3) ^ ((bcol1 >> 1) & 3);
    const unsigned short* bseg1 = Wt + (size_t)(c0 + bcol1) * IN_F + bchunk1 * 8;

    int a_off[2], b_off[4];
#pragma unroll
    for (int m = 0; m < 2; ++m) {
        int rl = wr * 32 + m * 16 + lrow;
        a_off[m] = rl * 64 + ((s ^ ((rl >> 1) & 3)) << 4);
    }
#pragma unroll
    for (int n = 0; n < 4; ++n) {
        int cl = wc * 64 + n * 16 + lrow;
        b_off[n] = cl * 64 + ((s ^ ((cl >> 1) & 3)) << 4);
    }

    // norm for this lane's 8 output rows
    float nrmv[2][4];
#pragma unroll
    for (int m = 0; m < 2; ++m)
#pragma unroll
        for (int r = 0; r < 4; ++r) {
            int rg = r0 + wr * 32 + m * 16 + s * 4 + r;
            nrmv[m][r] = norm[rg < N ? rg : N - 1];
        }

    f32x4 acc[2][4] = {};

    for (int kk = 0; kk < IN_F / BK; ++kk) {
        async_load16(aseg + kk * BK, Ab + tid * 16);
        async_load16(bseg0 + kk * BK, Bb + tid * 16);
        async_load16(bseg1 + kk * BK, Bb + (tid + 256) * 16);
        __syncthreads();

        bf16x8 af[2], bfv[4];
#pragma unroll
        for (int m = 0; m < 2; ++m) af[m] = *(const bf16x8*)(Ab + a_off[m]);
#pragma unroll
        for (int n = 0; n < 4; ++n) bfv[n] = *(const bf16x8*)(Bb + b_off[n]);
#pragma unroll
        for (int m = 0; m < 2; ++m)
#pragma unroll
            for (int n = 0; n < 4; ++n)
                acc[m][n] = __builtin_amdgcn_mfma_f32_16x16x32_bf16(af[m], bfv[n], acc[m][n], 0, 0, 0);
        __syncthreads();
    }

    // --- epilogue: bias+norm, stage bf16 tile in LDS (XOR-swizzled), coalesced store ---
    const bool doNorm = (c0 < 896);
#pragma unroll
    for (int m = 0; m < 2; ++m) {
        const int rowl = wr * 32 + m * 16 + s * 4;
#pragma unroll
        for (int n = 0; n < 4; ++n) {
            const int col = wc * 64 + n * 16 + lrow;
            const float bv = bvec[c0 + col];
            const int chunk = col >> 3, cb = col & 7;
#pragma unroll
            for (int r = 0; r < 4; ++r) {
                float v = acc[m][n][r] + bv;
                if (doNorm) v *= nrmv[m][r];
                const int row = rowl + r;
                Pst[row * 128 + ((chunk ^ (row & 7)) * 8 + cb)] = f2bf(v);
            }
        }
    }
    __syncthreads();

    const int ch = tid & 15;
#pragma unroll
    for (int rr = 0; rr < 4; ++rr) {
        const int rl = rr * 16 + (tid >> 4);
        const int rg = r0 + rl;
        if (rg < N) {
            uint4 v = *(const uint4*)&Pst[rl * 128 + ((ch ^ (rl & 7)) * 8)];
            *(uint4*)(P + (size_t)rg * NCOLS + c0 + ch * 8) = v;
        }
    }
}

// ---- histogram over dst ----
__global__ void k_hist(const int* __restrict__ dst, int* __restrict__ counts, int E) {
    int e = blockIdx.x * blockDim.x + threadIdx.x;
    if (e < E) atomicAdd(&counts[dst[e]], 1);
}

// ---- 3-phase exclusive scan over counts[N] ----
__global__ void __launch_bounds__(256) k_scan_a(const int* __restrict__ counts,
                                                int* __restrict__ offs,
                                                int* __restrict__ bsum, int N) {
    __shared__ int sm[256];
    int tid = threadIdx.x;
    int i = blockIdx.x * 256 + tid;
    int v = (i < N) ? counts[i] : 0;
    sm[tid] = v;
    __syncthreads();
#pragma unroll
    for (int st = 1; st < 256; st <<= 1) {
        int t = (tid >= st) ? sm[tid - st] : 0;
        __syncthreads();
        sm[tid] += t;
        __syncthreads();
    }
    if (i < N) offs[i] = sm[tid] - v;
    if (tid == 255) bsum[blockIdx.x] = sm[255];
}

__global__ void __launch_bounds__(256) k_scan_b(int* __restrict__ bsum, int NB) {
    __shared__ int sm[256];
    int tid = threadIdx.x;
    int v = (tid < NB) ? bsum[tid] : 0;
    sm[tid] = v;
    __syncthreads();
#pragma unroll
    for (int st = 1; st < 256; st <<= 1) {
        int t = (tid >= st) ? sm[tid - st] : 0;
        __syncthreads();
        sm[tid] += t;
        __syncthreads();
    }
    if (tid < NB) bsum[tid] = sm[tid] - v;
}

__global__ void k_scan_c(int* __restrict__ offs, const int* __restrict__ bsum,
                         int* __restrict__ cursor, int N) {
    int i = blockIdx.x * 256 + threadIdx.x;
    if (i >= N) return;
    int o = offs[i] + bsum[blockIdx.x];
    offs[i] = o;
    cursor[i] = o;
}

// ---- scatter edges into CSR order: pedge[slot] = {src, packed degs} ----
__global__ void k_scatter(const int* __restrict__ src, const int* __restrict__ dst,
                          const float* __restrict__ degrees,
                          int* __restrict__ cursor, uint2* __restrict__ pedge, int E) {
    int e = blockIdx.x * blockDim.x + threadIdx.x;
    if (e >= E) return;
    int d = dst[e];
    int slot = atomicAdd(&cursor[d], 1);
    unsigned pk = 0;
#pragma unroll
    for (int i = 0; i < 6; ++i) {
        float df = degrees[(size_t)e * 6 + i];
        pk |= ((unsigned)df) << (4 * i);
    }
    pedge[slot] = make_uint2((unsigned)src[e], pk);
}

// ---- aggregate: lane-parallel metadata + LDS gather worklist ----
__global__ void __launch_bounds__(256) k_aggregate(
    const unsigned short* __restrict__ P,
    const int* __restrict__ row_start, const int* __restrict__ counts,
    const uint2* __restrict__ pedge,
    const float* __restrict__ norm, const float* __restrict__ W_edge,
    const float* __restrict__ bias, float* __restrict__ out, int N)
{
    __shared__ unsigned EL[4][192];
    const int wid = threadIdx.x >> 6;
    const int n = blockIdx.x * 4 + wid;
    if (n >= N) return;
    const int lane = threadIdx.x & 63;
    unsigned* el = EL[wid];

    float2 w[6];
#pragma unroll
    for (int i = 0; i < 6; ++i) w[i] = *(const float2*)(W_edge + i * OUT_F + lane * 2);

    const int beg = row_start[n];
    const int end = beg + counts[n];
    const unsigned* __restrict__ Pd = (const unsigned*)P;

    float Swd[6] = {0.f, 0.f, 0.f, 0.f, 0.f, 0.f};
    float g0 = 0.f, g1 = 0.f;

    for (int p0 = beg; p0 < end; p0 += 64) {
        const int t = p0 + lane;
        const bool valid = t < end;
        uint2 pe = valid ? pedge[t] : make_uint2(0u, 0u);
        const unsigned dp = pe.y;
        const float nr = (dp != 0u) ? norm[pe.x] : 0.f;

        unsigned zm = 0;
#pragma unroll
        for (int i = 0; i < 6; ++i) {
            int d = (dp >> (4 * i)) & 15;
            if (d == 0) zm |= (1u << i);
            Swd[i] += nr * (float)d;
        }
        const int z = __popc(zm);
        const int ne = (dp == 0u) ? 0 : ((z <= 2) ? (1 + z) : (6 - z));

        int x = ne;
#pragma unroll
        for (int st = 1; st < 64; st <<= 1) {
            int v = __shfl_up(x, st);
            if (lane >= st) x += v;
        }
        const int excl = x - ne;
        const int total = __shfl(x, 63);

        if (ne) {
            const unsigned base = pe.x * 512u;
            int wp = excl;
            if (z <= 2) {
                el[wp++] = base + 384u;
#pragma unroll
                for (int i = 0; i < 6; ++i)
                    if ((zm >> i) & 1u) el[wp++] = (base + i * 64u) | 0x80000000u;
            } else {
#pragma unroll
                for (int i = 0; i < 6; ++i)
                    if (!((zm >> i) & 1u)) el[wp++] = base + i * 64u;
            }
        }
        asm volatile("s_waitcnt lgkmcnt(0)" ::: "memory");

        int j = 0;
        for (; j + 4 <= total; j += 4) {
            unsigned e0 = el[j], e1 = el[j + 1], e2 = el[j + 2], e3 = el[j + 3];
            unsigned u0 = Pd[(e0 & 0x7fffffffu) + lane];
            unsigned u1 = Pd[(e1 & 0x7fffffffu) + lane];
            unsigned u2 = Pd[(e2 & 0x7fffffffu) + lane];
            unsigned u3 = Pd[(e3 & 0x7fffffffu) + lane];
            float s0 = __uint_as_float(0x3f800000u | (e0 & 0x80000000u));
            float s1 = __uint_as_float(0x3f800000u | (e1 & 0x80000000u));
            float s2 = __uint_as_float(0x3f800000u | (e2 & 0x80000000u));
            float s3 = __uint_as_float(0x3f800000u | (e3 & 0x80000000u));
            g0 += s0 * bf_lo(u0); g1 += s0 * bf_hi(u0);
            g0 += s1 * bf_lo(u1); g1 += s1 * bf_hi(u1);
            g0 += s2 * bf_lo(u2); g1 += s2 * bf_hi(u2);
            g0 += s3 * bf_lo(u3); g1 += s3 * bf_hi(u3);
        }
        for (; j < total; ++j) {
            unsigned e0 = el[j];
            unsigned u0 = Pd[(e0 & 0x7fffffffu) + lane];
            float s0 = __uint_as_float(0x3f800000u | (e0 & 0x80000000u));
            g0 += s0 * bf_lo(u0); g1 += s0 * bf_hi(u0);
        }
    }

    float b0 = 0.f, b1 = 0.f;
#pragma unroll
    for (int i = 0; i < 6; ++i) {
        float v = Swd[i];
#pragma unroll
        for (int st = 1; st < 64; st <<= 1) v += __shfl_xor(v, st);
        b0 += v * w[i].x;
        b1 += v * w[i].y;
    }

    const unsigned us = Pd[(size_t)n * 512 + 448 + lane];
    const float nd = norm[n];
    const float2 bv = *(const float2*)(bias + lane * 2);
    float2 o;
    o.x = fmaxf((g0 + b0) * nd + bf_lo(us) + bv.x, 0.f);
    o.y = fmaxf((g1 + b1) * nd + bf_hi(us) + bv.y, 0.f);
    *(float2*)(out + (size_t)n * OUT_F + lane * 2) = o;
}

extern "C" void kernel_launch(void* const* d_in, const int* in_sizes, int n_in,
                              void* d_out, int out_size, void* d_ws, size_t ws_size,
                              hipStream_t stream)
{
    const float* h       = (const float*)d_in[0];
    const float* degrees = (const float*)d_in[1];
    const float* norm    = (const float*)d_in[2];
    const int*   src     = (const int*)d_in[3];
    const int*   dst     = (const int*)d_in[4];
    const float* W_self  = (const float*)d_in[5];
    const float* b_self  = (const float*)d_in[6];
    const float* W_node  = (const float*)d_in[7];
    const float* b_node  = (const float*)d_in[8];
    const float* W_edge  = (const float*)d_in[9];
    const float* bias    = (const float*)d_in[10];
    float* out = (float*)d_out;

    const int N = in_sizes[2];   // norm [N,1]
    const int E = in_sizes[3];   // src [E]
    const int NB = (N + 255) / 256;

    char* ws = (char*)d_ws;
    size_t off = 0;
    auto alloc = [&](size_t sz) { size_t o = off; off = (off + sz + 255) & ~(size_t)255; return o; };
    unsigned short* P      = (unsigned short*)(ws + alloc((size_t)N * NCOLS * 2)); // 102.4 MB
    unsigned short* hb     = (unsigned short*)(ws + alloc((size_t)N * IN_F * 2));  // 25.6 MB
    unsigned short* Wt     = (unsigned short*)(ws + alloc((size_t)NCOLS * IN_F * 2));
    float*          bvec   = (float*)(ws + alloc(NCOLS * 4));
    int*            counts = (int*)(ws + alloc((size_t)N * 4));
    int*            offs   = (int*)(ws + alloc((size_t)N * 4));
    int*            cursor = (int*)(ws + alloc((size_t)N * 4));
    int*            bsum   = (int*)(ws + alloc((size_t)NB * 4));
    uint2*          pedge  = (uint2*)(ws + alloc((size_t)E * 8));                  // 6.4 MB

    hipMemsetAsync(counts, 0, (size_t)N * 4, stream);

    int t8 = N * (IN_F / 8);
    k_conv_h<<<(t8 + 255) / 256, 256, 0, stream>>>(h, hb, t8);

    int tw = IN_F * NCOLS;
    k_conv_w<<<(tw + 255) / 256, 256, 0, stream>>>(W_node, W_self, Wt, tw);
    k_conv_b<<<(NCOLS + 255) / 256, 256, 0, stream>>>(b_node, b_self, bvec);

    // XCD-chunked swizzled grid: rowsPerXcd row-strips per XCD, 8 col-blocks each
    const int R  = (N + BM - 1) / BM;        // 782 row-strips
    const int RP = (R + 7) / 8;              // 98 per XCD (padded; overflow blocks exit)
    k_gemm<<<RP * 8 * 8, 256, 0, stream>>>(hb, Wt, bvec, norm, P, N, RP);

    k_hist<<<(E + 255) / 256, 256, 0, stream>>>(dst, counts, E);
    k_scan_a<<<NB, 256, 0, stream>>>(counts, offs, bsum, N);
    k_scan_b<<<1, 256, 0, stream>>>(bsum, NB);
    k_scan_c<<<NB, 256, 0, stream>>>(offs, bsum, cursor, N);
    k_scatter<<<(E + 255) / 256, 256, 0, stream>>>(src, dst, degrees, cursor, pedge, E);

    k_aggregate<<<(N + 3) / 4, 256, 0, stream>>>(P, offs, counts, pedge, norm, W_edge, bias, out, N);
}